// Round 12
// baseline (227.388 us; speedup 1.0000x reference)
//
#include <hip/hip_runtime.h>
#include <hip/hip_bf16.h>
#include <math.h>

// Problem constants
#define Bb 4
#define Nn 1025
#define Cc 768
#define Hh 12
#define BH (Bb*Hh)          // 48
#define M_ROWS 4100
#define KSEL 256            // int(1024*0.25)
#define JP 1152             // padded j (9 sweeps x 128)
#define IT_TILES 68         // qB i-tiles of 16 (i < 1088)
#define NIB 17              // ctx i-blocks of 64
#define NIB32 33            // colsum i-blocks of 32
#define NSW 9               // j-sweeps of 128
#define MT16 264            // padded M tiles of 16 (4224 rows)
#define KC24 24             // 768/32 k-chunks
#define JT16 72             // j 16-tiles (1152/16)
#define ESTR 1160           // expS row stride (bf16)
#define NPART 396           // partial rows per batch (12 h * 33 ib)
#define QSCALE 0.18033688011112042f   // 0.125 * log2(e): S is in log2 domain

// cast_all region sizes (in 256-thread blocks)
#define CAST_X_BLK 1584     // 405,504 slots
#define CAST_WQKV_BLK 864   // 221,184 slots
#define CAST_WPROJ_BLK 288  // 73,728 slots

typedef __attribute__((ext_vector_type(8))) short short8;
typedef __attribute__((ext_vector_type(4))) short short4s;
typedef __attribute__((ext_vector_type(4))) float floatx4;

static __device__ inline unsigned short f2bf(float v) {       // RNE
    __hip_bfloat16 b = __float2bfloat16(v);
    return *reinterpret_cast<unsigned short*>(&b);
}
static __device__ inline short tbfs(float f) {                // truncate (fast)
    union { float f; unsigned u; } x; x.f = f;
    return (short)(x.u >> 16);
}
static __device__ inline unsigned short tbf(float f) {
    union { float f; unsigned u; } x; x.f = f;
    return (unsigned short)(x.u >> 16);
}
static __device__ inline float fexp2(float x) {
    return __builtin_amdgcn_exp2f(x);
}
static __device__ inline float bflo(unsigned u) {
    return __uint_as_float((u & 0xffffu) << 16);
}
static __device__ inline float bfhi(unsigned u) {
    return __uint_as_float(u & 0xffff0000u);
}

// async global->LDS, 16B per lane; lds dest must be wave-uniform base
static __device__ inline void async16(const unsigned short* g, unsigned short* l) {
    __builtin_amdgcn_global_load_lds(
        (const __attribute__((address_space(1))) unsigned int*)g,
        (__attribute__((address_space(3))) unsigned int*)l, 16, 0, 0);
}

// ---------------------------------------------------------------------------
// Fused input casts: x -> xA (A-frag), Wqkv -> WB (B-frag), Wproj -> WpB.
// Pads elsewhere (qB/kF/vF/ctxA) stay 0xAA poison — poison bf16 is ~2^-85
// (finite tiny) and every pad read downstream is masked.
__global__ __launch_bounds__(256)
void cast_all(const float* __restrict__ x, const float* __restrict__ Wqkv,
              const float* __restrict__ Wproj,
              unsigned short* __restrict__ xA, unsigned short* __restrict__ WB,
              unsigned short* __restrict__ WpB)
{
    int blk = blockIdx.x;
    int tid = threadIdx.x;
    if (blk < CAST_X_BLK) {
        int s = blk * 256 + tid;                    // < 405504
        int ml = s & 15, q = (s >> 4) & 3;
        int t2 = s >> 6;
        int mt = t2 % MT16, kc = t2 / MT16;
        int m = mt * 16 + ml, k = kc * 32 + q * 8;
        uint4 pk = {0u, 0u, 0u, 0u};
        if (m < M_ROWS) {
            float4 a = *(const float4*)&x[(size_t)m * 768 + k];
            float4 b2 = *(const float4*)&x[(size_t)m * 768 + k + 4];
            pk.x = (unsigned)f2bf(a.x)  | ((unsigned)f2bf(a.y)  << 16);
            pk.y = (unsigned)f2bf(a.z)  | ((unsigned)f2bf(a.w)  << 16);
            pk.z = (unsigned)f2bf(b2.x) | ((unsigned)f2bf(b2.y) << 16);
            pk.w = (unsigned)f2bf(b2.z) | ((unsigned)f2bf(b2.w) << 16);
        }
        *(uint4*)&xA[(size_t)s * 8] = pk;
        return;
    }
    const float* W;
    unsigned short* WO;
    int N, NT, s;
    if (blk < CAST_X_BLK + CAST_WQKV_BLK) {
        W = Wqkv; WO = WB; N = 2304; NT = 144;
        s = (blk - CAST_X_BLK) * 256 + tid;
    } else {
        W = Wproj; WO = WpB; N = 768; NT = 48;
        s = (blk - CAST_X_BLK - CAST_WQKV_BLK) * 256 + tid;
    }
    int nl = s & 15, q = (s >> 4) & 3;
    int t2 = s >> 6;
    int nt = t2 % NT, kc = t2 / NT;
    int n = nt * 16 + nl, k = kc * 32 + q * 8;
    unsigned hv[8];
#pragma unroll
    for (int e = 0; e < 8; ++e)
        hv[e] = f2bf(W[(size_t)(k + e) * N + n]);
    uint4 pk;
    pk.x = hv[0] | (hv[1] << 16);
    pk.y = hv[2] | (hv[3] << 16);
    pk.z = hv[4] | (hv[5] << 16);
    pk.w = hv[6] | (hv[7] << 16);
    *(uint4*)&WO[(size_t)s * 8] = pk;
}

// ---------------------------------------------------------------------------
// MFMA bf16 GEMM, 128x128 tile, 4 waves x (4x4 of 16x16x32), BK=32.
// mode 0 scatters: qB (B-frag x32, xQSCALE), kF (A-frag x32),
//                  vF (B-frag for 16x16x16: k=j quad*4+e, n=d&15)
__global__ __launch_bounds__(256, 2)
void gemm_mfma(const unsigned short* __restrict__ Af,
               const unsigned short* __restrict__ Bf,
               int Nt16, int mode,
               unsigned short* __restrict__ qB, unsigned short* __restrict__ kF,
               unsigned short* __restrict__ vF,
               float* __restrict__ outp, const float* __restrict__ bias)
{
    __shared__ __align__(16) unsigned short ldsA[4096];
    __shared__ __align__(16) unsigned short ldsB[4096];
    const int tid = threadIdx.x;
    const int ln = tid & 63, w = tid >> 6;
    const int wm = w >> 1, wn = w & 1;
    const int mb = blockIdx.x, nb = blockIdx.y;

    floatx4 acc[4][4];
#pragma unroll
    for (int mt = 0; mt < 4; ++mt)
#pragma unroll
        for (int nt = 0; nt < 4; ++nt)
            acc[mt][nt] = (floatx4){0.f, 0.f, 0.f, 0.f};

    for (int kc = 0; kc < KC24; ++kc) {
        const unsigned short* gA = Af + ((size_t)(kc * MT16 + mb * 8)) * 512;
        const unsigned short* gB = Bf + ((size_t)(kc * Nt16 + nb * 8)) * 512;
        async16(gA + (size_t)(w * 128 + ln) * 8,      &ldsA[w * 1024]);
        async16(gA + (size_t)(w * 128 + 64 + ln) * 8, &ldsA[w * 1024 + 512]);
        async16(gB + (size_t)(w * 128 + ln) * 8,      &ldsB[w * 1024]);
        async16(gB + (size_t)(w * 128 + 64 + ln) * 8, &ldsB[w * 1024 + 512]);
        __syncthreads();

        short8 Am[4], Bn[4];
#pragma unroll
        for (int mt = 0; mt < 4; ++mt)
            Am[mt] = *(const short8*)&ldsA[((wm * 4 + mt) * 64 + ln) * 8];
#pragma unroll
        for (int nt = 0; nt < 4; ++nt)
            Bn[nt] = *(const short8*)&ldsB[((wn * 4 + nt) * 64 + ln) * 8];
#pragma unroll
        for (int mt = 0; mt < 4; ++mt)
#pragma unroll
            for (int nt = 0; nt < 4; ++nt)
                acc[mt][nt] = __builtin_amdgcn_mfma_f32_16x16x32_bf16(
                    Am[mt], Bn[nt], acc[mt][nt], 0, 0, 0);
        __syncthreads();
    }

    const int q = ln >> 4, l15 = ln & 15;
    if (mode == 1) {
#pragma unroll
        for (int nt = 0; nt < 4; ++nt) {
            int gn = nb * 128 + wn * 64 + nt * 16 + l15;
            float bv = bias[gn];
#pragma unroll
            for (int mt = 0; mt < 4; ++mt) {
                int gmb = mb * 128 + wm * 64 + mt * 16 + q * 4;
#pragma unroll
                for (int r = 0; r < 4; ++r) {
                    int gm = gmb + r;
                    if (gm < M_ROWS)
                        outp[(size_t)gm * 768 + gn] = acc[mt][nt][r] + bv;
                }
            }
        }
    } else {
#pragma unroll
        for (int nt = 0; nt < 4; ++nt) {
            int gn = nb * 128 + wn * 64 + nt * 16 + l15;
            int s = (gn >= 1536) ? 2 : (gn >= 768 ? 1 : 0);
            int rr = gn - s * Cc;
            int h = rr >> 6, d = rr & 63;
#pragma unroll
            for (int mt = 0; mt < 4; ++mt) {
                int gmb = mb * 128 + wm * 64 + mt * 16 + q * 4;
#pragma unroll
                for (int r = 0; r < 4; ++r) {
                    int gm = gmb + r;
                    if (gm >= M_ROWS) continue;
                    int b = gm / Nn;
                    int n = gm - b * Nn;
                    int bh = b * Hh + h;
                    float val = acc[mt][nt][r];
                    if (s == 0) {
                        int idx = (((bh * IT_TILES + (n >> 4)) * 2 + (d >> 5)) * 512)
                                  + ((((d & 31) >> 3) * 16 + (n & 15)) * 8) + (d & 7);
                        qB[idx] = f2bf(val * QSCALE);
                    } else if (s == 1) {
                        size_t idx = ((((size_t)bh * JT16 + (n >> 4)) * 2 + (d >> 5)) * 64
                                      + ((d >> 3) & 3) * 16 + (n & 15)) * 8 + (d & 7);
                        kF[idx] = f2bf(val);
                    } else {
                        // V as 16x16x16 B-frag: tile=(n>>4), dt=(d>>4),
                        // lane=((n>>2)&3)*16 + (d&15), elem=n&3
                        size_t idx = ((((size_t)bh * JT16 + (n >> 4)) * 4 + (d >> 4)) * 64
                                      + ((n >> 2) & 3) * 16 + (d & 15)) * 4 + (n & 3);
                        vF[idx] = f2bf(val);
                    }
                }
            }
        }
    }
}

// ---------------------------------------------------------------------------
// Pass A: SINGLE-QK colsum, no global atomics (per-block partial rows).
__global__ __launch_bounds__(256, 2)
void attn_colsum_mfma(const unsigned short* __restrict__ qB,
                      const unsigned short* __restrict__ kF,
                      float* __restrict__ colsum_part)
{
    __shared__ unsigned short expS[32 * ESTR];    // 74,240 B  [i][j] bf16
    __shared__ float red16[16][32];
    __shared__ float linv[32];

    const int blk = blockIdx.x;                 // 1584 = 8 * 198
    const int x8 = blk & 7, g = blk >> 3;
    const int bh = x8 * 6 + (g % 6);
    const int ib = g / 6;                        // 0..32
    const int tid = threadIdx.x;
    const int ws = tid >> 6;
    const int ln = tid & 63;
    const int i16 = ln & 15, q = ln >> 4;

    const unsigned short* kBase = kF + (size_t)bh * JT16 * 1024;

    short8 Qf[2][2];
#pragma unroll
    for (int it = 0; it < 2; ++it)
#pragma unroll
        for (int kc = 0; kc < 2; ++kc)
            Qf[it][kc] = *(const short8*)&qB[(((size_t)bh * IT_TILES + ib * 2 + it) * 2 + kc) * 512 + ln * 8];

    float lacc[2][2] = {{0.f, 0.f}, {0.f, 0.f}};

    short8 Kc[2][2], Kn[2][2];
#pragma unroll
    for (int jt = 0; jt < 2; ++jt)
#pragma unroll
        for (int kc = 0; kc < 2; ++kc)
            Kc[jt][kc] = *(const short8*)&kBase[(((ws * 2 + jt) * 2 + kc) * 64 + ln) * 8];

    for (int sw = 0; sw < NSW; ++sw) {
        if (sw + 1 < NSW) {
#pragma unroll
            for (int jt = 0; jt < 2; ++jt)
#pragma unroll
                for (int kc = 0; kc < 2; ++kc)
                    Kn[jt][kc] = *(const short8*)&kBase[((((sw + 1) * 8 + ws * 2 + jt) * 2 + kc) * 64 + ln) * 8];
        }

        floatx4 S[2][2];
#pragma unroll
        for (int it = 0; it < 2; ++it)
#pragma unroll
            for (int jt = 0; jt < 2; ++jt) {
                S[it][jt] = (floatx4){0.f, 0.f, 0.f, 0.f};
#pragma unroll
                for (int kc = 0; kc < 2; ++kc)
                    S[it][jt] = __builtin_amdgcn_mfma_f32_16x16x32_bf16(Kc[jt][kc], Qf[it][kc], S[it][jt], 0, 0, 0);
            }

        const int jbase0 = sw * 128 + ws * 32 + q * 4;
#pragma unroll
        for (int it = 0; it < 2; ++it) {
            const int irow = it * 16 + i16;
#pragma unroll
            for (int jt = 0; jt < 2; ++jt) {
                int jbase = jbase0 + jt * 16;
                float p[4];
#pragma unroll
                for (int r = 0; r < 4; ++r) {
                    float vld = (jbase + r < Nn) ? 1.f : 0.f;
                    p[r] = fexp2(S[it][jt][r]) * vld;
                }
                lacc[it][jt] += (p[0] + p[1]) + (p[2] + p[3]);
                uint2 pk;
                pk.x = (unsigned)tbf(p[0]) | ((unsigned)tbf(p[1]) << 16);
                pk.y = (unsigned)tbf(p[2]) | ((unsigned)tbf(p[3]) << 16);
                *(uint2*)&expS[irow * ESTR + jbase] = pk;
            }
        }
#pragma unroll
        for (int jt = 0; jt < 2; ++jt)
#pragma unroll
            for (int kc = 0; kc < 2; ++kc)
                Kc[jt][kc] = Kn[jt][kc];
    }

    __syncthreads();
#pragma unroll
    for (int it = 0; it < 2; ++it)
        red16[ws * 4 + q][it * 16 + i16] = lacc[it][0] + lacc[it][1];
    __syncthreads();
    if (tid < 32) {
        float s = 0.f;
#pragma unroll
        for (int t = 0; t < 16; ++t) s += red16[t][tid];
        int gi = ib * 32 + tid;
        linv[tid] = (gi < Nn) ? 1.f / s : 0.f;
    }
    __syncthreads();

    float* prow = colsum_part + (size_t)(bh * NIB32 + ib) * JP;
    for (int grp = tid; grp < 288; grp += 256) {
        int j0 = grp * 4;
        float a0 = 0.f, a1 = 0.f, a2 = 0.f, a3 = 0.f;
#pragma unroll 8
        for (int i = 0; i < 32; ++i) {
            uint2 v = *(const uint2*)&expS[i * ESTR + j0];
            float li = linv[i];
            a0 += bflo(v.x) * li;
            a1 += bfhi(v.x) * li;
            a2 += bflo(v.y) * li;
            a3 += bfhi(v.y) * li;
        }
        float4 o = {a0, a1, a2, a3};
        *(float4*)&prow[j0] = o;
    }
}

// ---------------------------------------------------------------------------
// UCB: self-zeroes keepP/cnt_b rows (ws is poison!), reduces 396 partials,
// scores, exact top-256 per batch.  cnt_b is per-batch (no atomics).
__global__ __launch_bounds__(1024)
void ucb_topk(const float* __restrict__ colsum_part, const float* __restrict__ ucb_score,
              const int* __restrict__ counter_p,
              float* __restrict__ keepP, float* __restrict__ cnt_b)
{
    const int b = blockIdx.x;
    const int tid = threadIdx.x;
    __shared__ float vals[1024];
    __shared__ int   idxs[1024];

    for (int t = tid; t < JP; t += 1024) {
        keepP[b * JP + t] = 0.f;
        cnt_b[b * JP + t] = 0.f;
    }

    const int j = tid + 1;
    const float* pb = colsum_part + (size_t)b * NPART * JP + j;
    float c0 = 0.f, c1 = 0.f, c2 = 0.f, c3 = 0.f;
#pragma unroll 4
    for (int g2 = 0; g2 < NPART; g2 += 4) {
        c0 += pb[(size_t)(g2 + 0) * JP];
        c1 += pb[(size_t)(g2 + 1) * JP];
        c2 += pb[(size_t)(g2 + 2) * JP];
        c3 += pb[(size_t)(g2 + 3) * JP];
    }
    float cs = (c0 + c1) + (c2 + c3);

    float lc = logf((float)(*counter_p) + 1.0f);
    float s = cs * (1.0f / (float)Nn);
#pragma unroll
    for (int h = 0; h < Hh; ++h)
        s += sqrtf(lc / (ucb_score[h * Nn + j] + 1e-6f));
    s *= (1.0f / (float)Hh);
    vals[tid] = s; idxs[tid] = tid;
    __syncthreads();

    for (int k = 2; k <= 1024; k <<= 1) {
        for (int jj = k >> 1; jj > 0; jj >>= 1) {
            int partner = tid ^ jj;
            if (partner > tid) {
                float v1 = vals[tid], v2 = vals[partner];
                int i1 = idxs[tid], i2 = idxs[partner];
                bool gt = (v1 > v2) || (v1 == v2 && i1 < i2);
                bool desc = ((tid & k) == 0);
                if (desc ? !gt : gt) {
                    vals[tid] = v2; vals[partner] = v1;
                    idxs[tid] = i2; idxs[partner] = i1;
                }
            }
            __syncthreads();
        }
    }

    if (tid < KSEL) {
        int tok = idxs[tid] + 1;
        keepP[b * JP + tok] = 1.f;
        cnt_b[b * JP + tok] = 1.0f / (float)Bb;    // unique tokens: plain store
    }
    if (tid == 0) keepP[b * JP + 0] = 1.f;
}

// ---------------------------------------------------------------------------
// Pass B: masked renormalized context.  64-row i-blocks, grid 816 XCD-
// swizzled, register-double-buffered K/V.  P feeds PV DIRECTLY via
// mfma_f32_16x16x16bf16_1k (A-layout k=quad*4+e == S C-layout rows) —
// no P LDS round-trip.  launch_bounds(256,2): (256,3) spills (R10).
__global__ __launch_bounds__(256, 2)
void attn_ctx_mfma(const unsigned short* __restrict__ qB,
                   const unsigned short* __restrict__ kF,
                   const unsigned short* __restrict__ vF,
                   const float* __restrict__ keepP, const float* __restrict__ cnt_b,
                   unsigned short* __restrict__ ctxA, float* __restrict__ out2)
{
    __shared__ __align__(16) char smem[25856];
    float* keeps = (float*)smem;                             // [1152] 4608 B
    float* red16 = (float*)(smem + 4608);                    // [16][64] 4096 B
    float* dinv  = (float*)(smem + 8704);                    // [64] 256 B
    float* redC  = (float*)(smem + 8960);                    // [64][66] 16896 B

    const int blk = blockIdx.x;                 // 816 = 8 * 102
    const int x8 = blk & 7, g = blk >> 3;
    const int bh = x8 * 6 + (g % 6);
    const int ib = g / 6;
    const int b = bh / Hh, h = bh % Hh;
    const int tid = threadIdx.x;
    const int ws = tid >> 6;
    const int ln = tid & 63;
    const int i16 = ln & 15, q = ln >> 4;

    // fused score_delta write (out2[t] = sum_b cnt_b[b][t%Nn])
    {
        int t = blk * 256 + tid;
        if (t < Hh * Nn) {
            int n = t % Nn;
            out2[t] = cnt_b[0 * JP + n] + cnt_b[1 * JP + n]
                    + cnt_b[2 * JP + n] + cnt_b[3 * JP + n];
        }
    }

    for (int t = tid; t < JP; t += 256) keeps[t] = keepP[b * JP + t];

    const unsigned short* kBase = kF + (size_t)bh * JT16 * 1024;
    const unsigned short* vBase = vF + (size_t)bh * JT16 * 1024;   // same extent

    short8 Qf[4][2];
#pragma unroll
    for (int it = 0; it < 4; ++it)
#pragma unroll
        for (int kc = 0; kc < 2; ++kc)
            Qf[it][kc] = *(const short8*)&qB[(((size_t)bh * IT_TILES + ib * 4 + it) * 2 + kc) * 512 + ln * 8];

    __syncthreads();                     // keeps staged

    float keepi[4];
#pragma unroll
    for (int it = 0; it < 4; ++it)
        keepi[it] = keeps[(ib * 4 + it) * 16 + i16];

    floatx4 ctxacc[4][4];
#pragma unroll
    for (int it = 0; it < 4; ++it)
#pragma unroll
        for (int dt = 0; dt < 4; ++dt)
            ctxacc[it][dt] = (floatx4){0.f, 0.f, 0.f, 0.f};
    float dsacc[4] = {0.f, 0.f, 0.f, 0.f};

    short8 Kc[2][2], Kn[2][2];
    short4s Vc[2][4], Vn[2][4];
#pragma unroll
    for (int jt = 0; jt < 2; ++jt) {
#pragma unroll
        for (int kc = 0; kc < 2; ++kc)
            Kc[jt][kc] = *(const short8*)&kBase[(((ws * 2 + jt) * 2 + kc) * 64 + ln) * 8];
#pragma unroll
        for (int dt = 0; dt < 4; ++dt)
            Vc[jt][dt] = *(const short4s*)&vBase[(((ws * 2 + jt) * 4 + dt) * 64 + ln) * 4];
    }

    for (int sw = 0; sw < NSW; ++sw) {
        if (sw + 1 < NSW) {
#pragma unroll
            for (int jt = 0; jt < 2; ++jt) {
#pragma unroll
                for (int kc = 0; kc < 2; ++kc)
                    Kn[jt][kc] = *(const short8*)&kBase[((((sw + 1) * 8 + ws * 2 + jt) * 2 + kc) * 64 + ln) * 8];
#pragma unroll
                for (int dt = 0; dt < 4; ++dt)
                    Vn[jt][dt] = *(const short4s*)&vBase[((((sw + 1) * 8 + ws * 2 + jt) * 4 + dt) * 64 + ln) * 4];
            }
        }

        float kjv[2][4], vld[2][4];
#pragma unroll
        for (int jt = 0; jt < 2; ++jt)
#pragma unroll
            for (int r = 0; r < 4; ++r) {
                int jj = sw * 128 + ws * 32 + jt * 16 + q * 4 + r;
                vld[jt][r] = (jj < Nn) ? 1.f : 0.f;
                kjv[jt][r] = keeps[jj];
            }

#pragma unroll
        for (int it = 0; it < 4; ++it) {
            floatx4 S[2];
#pragma unroll
            for (int jt = 0; jt < 2; ++jt) {
                S[jt] = (floatx4){0.f, 0.f, 0.f, 0.f};
#pragma unroll
                for (int kc = 0; kc < 2; ++kc)
                    S[jt] = __builtin_amdgcn_mfma_f32_16x16x32_bf16(Kc[jt][kc], Qf[it][kc], S[jt], 0, 0, 0);
            }
            bool rk = keepi[it] > 0.5f;
#pragma unroll
            for (int jt = 0; jt < 2; ++jt) {
                float p[4];
#pragma unroll
                for (int r = 0; r < 4; ++r) {
                    float w = rk ? vld[jt][r] : kjv[jt][r];
                    p[r] = fexp2(S[jt][r]) * w;
                    dsacc[it] += p[r];
                }
                short4s Pa;
                Pa.x = tbfs(p[0]); Pa.y = tbfs(p[1]);
                Pa.z = tbfs(p[2]); Pa.w = tbfs(p[3]);
#pragma unroll
                for (int dt = 0; dt < 4; ++dt)
                    ctxacc[it][dt] = __builtin_amdgcn_mfma_f32_16x16x16bf16_1k(
                        Pa, Vc[jt][dt], ctxacc[it][dt], 0, 0, 0);
            }
        }

#pragma unroll
        for (int jt = 0; jt < 2; ++jt) {
#pragma unroll
            for (int kc = 0; kc < 2; ++kc)
                Kc[jt][kc] = Kn[jt][kc];
#pragma unroll
            for (int dt = 0; dt < 4; ++dt)
                Vc[jt][dt] = Vn[jt][dt];
        }
    }

    // denominator reduce
    __syncthreads();
#pragma unroll
    for (int it = 0; it < 4; ++it) red16[(ws * 4 + q) * 64 + it * 16 + i16] = dsacc[it];
    __syncthreads();
    if (tid < 64) {
        float s = 0.f;
#pragma unroll
        for (int t = 0; t < 16; ++t) s += red16[t * 64 + tid];
        dinv[tid] = 1.f / (s + 1e-8f);
    }
    // cross-wave ctx reduce into redC
    for (int w = 0; w < 4; ++w) {
        __syncthreads();
        if (ws == w) {
#pragma unroll
            for (int it = 0; it < 4; ++it)
#pragma unroll
                for (int dt = 0; dt < 4; ++dt)
#pragma unroll
                    for (int r = 0; r < 4; ++r) {
                        int i = it * 16 + q * 4 + r;
                        int d = dt * 16 + i16;
                        float v = ctxacc[it][dt][r];
                        redC[i * 66 + d] = (w == 0) ? v : (redC[i * 66 + d] + v);
                    }
        }
    }
    __syncthreads();
    // write ctxA in A-fragment order: m = b*Nn+gi, k = h*64+d
#pragma unroll
    for (int rep = 0; rep < 2; ++rep) {
        int s2 = tid + rep * 256;          // < 512 : i(6b) x dc(3b)
        int i = s2 >> 3, dc = s2 & 7;
        int gi = ib * 64 + i;
        if (gi < Nn) {
            int m = b * Nn + gi;
            float dv = dinv[i];
            const float* src = &redC[i * 66 + dc * 8];
            uint4 pk;
            pk.x = (unsigned)f2bf(src[0] * dv) | ((unsigned)f2bf(src[1] * dv) << 16);
            pk.y = (unsigned)f2bf(src[2] * dv) | ((unsigned)f2bf(src[3] * dv) << 16);
            pk.z = (unsigned)f2bf(src[4] * dv) | ((unsigned)f2bf(src[5] * dv) << 16);
            pk.w = (unsigned)f2bf(src[6] * dv) | ((unsigned)f2bf(src[7] * dv) << 16);
            int kc2 = h * 2 + (dc >> 2);
            int q2 = dc & 3;
            size_t idx = (((size_t)(kc2 * MT16 + (m >> 4))) * 64 + q2 * 16 + (m & 15)) * 8;
            *(uint4*)&ctxA[idx] = pk;
        }
    }
}

// ---------------------------------------------------------------------------
extern "C" void kernel_launch(void* const* d_in, const int* in_sizes, int n_in,
                              void* d_out, int out_size, void* d_ws, size_t ws_size,
                              hipStream_t stream) {
    const float* x     = (const float*)d_in[0];
    const float* ucb   = (const float*)d_in[1];
    const float* Wqkv  = (const float*)d_in[2];
    const float* Wproj = (const float*)d_in[3];
    const float* bproj = (const float*)d_in[4];
    const int*   counter = (const int*)d_in[5];

    unsigned short* qB = (unsigned short*)d_ws;      // 3,342,336 sh
    unsigned short* kF = qB + 3342336;               // 3,538,944 sh
    unsigned short* vF = kF + 3538944;               // 3,538,944 sh
    float* keepP    = (float*)(vF + 3538944);        // 4608 f
    float* cnt_b    = keepP + 4608;                  // 4608 f
    unsigned short* ctxA = (unsigned short*)(cnt_b + 4608);  // 3,244,032 sh
    unsigned short* xA   = ctxA + 3244032;           // 3,244,032 sh
    unsigned short* WB   = xA + 3244032;             // 1,769,472 sh
    unsigned short* WpB  = WB + 1769472;             // 589,824 sh
    float* colsum_part = (float*)(WpB + 589824);     // 1,824,768 f

    float* out  = (float*)d_out;                     // [B,N,C]
    float* out2 = out + 3148800;                     // [H,N]

    cast_all<<<dim3(CAST_X_BLK + CAST_WQKV_BLK + CAST_WPROJ_BLK), dim3(256), 0, stream>>>(
        x, Wqkv, Wproj, xA, WB, WpB);
    gemm_mfma<<<dim3(33, 18), dim3(256), 0, stream>>>(
        xA, WB, 144, 0, qB, kF, vF, nullptr, nullptr);
    attn_colsum_mfma<<<dim3(8 * 198), dim3(256), 0, stream>>>(qB, kF, colsum_part);
    ucb_topk<<<dim3(Bb), dim3(1024), 0, stream>>>(colsum_part, ucb, counter, keepP, cnt_b);
    attn_ctx_mfma<<<dim3(8 * 102), dim3(256), 0, stream>>>(qB, kF, vF, keepP, cnt_b, ctxA, out2);
    gemm_mfma<<<dim3(33, 6), dim3(256), 0, stream>>>(
        ctxA, WpB, 48, 1, nullptr, nullptr, nullptr, out, bproj);
}

// Round 13
// 224.698 us; speedup vs baseline: 1.0120x; 1.0120x over previous
//
#include <hip/hip_runtime.h>
#include <hip/hip_bf16.h>
#include <math.h>

// Problem constants
#define Bb 4
#define Nn 1025
#define Cc 768
#define Hh 12
#define BH (Bb*Hh)          // 48
#define M_ROWS 4100
#define KSEL 256            // int(1024*0.25)
#define JP 1152             // padded j (9 sweeps x 128)
#define IT_TILES 68         // qB i-tiles of 16 (i < 1088)
#define NIB 17              // ctx i-blocks of 64
#define NIB32 33            // colsum i-blocks of 32
#define NSW 9               // j-sweeps of 128
#define MT16 264            // padded M tiles of 16 (4224 rows)
#define KC24 24             // 768/32 k-chunks
#define JT16 72             // j 16-tiles (1152/16)
#define STR4 292            // expS8 row stride in u32 (288 used + 4 pad)
#define NPART 396           // partial rows per batch (12 h * 33 ib)
#define QSCALE 0.18033688011112042f   // 0.125 * log2(e): S is in log2 domain

// cast_all region sizes (in 256-thread blocks)
#define CAST_X_BLK 1584     // 405,504 slots
#define CAST_WQKV_BLK 864   // 221,184 slots
#define CAST_WPROJ_BLK 288  // 73,728 slots

typedef __attribute__((ext_vector_type(8))) short short8;
typedef __attribute__((ext_vector_type(4))) short short4s;
typedef __attribute__((ext_vector_type(4))) float floatx4;

static __device__ inline unsigned short f2bf(float v) {       // RNE
    __hip_bfloat16 b = __float2bfloat16(v);
    return *reinterpret_cast<unsigned short*>(&b);
}
static __device__ inline short tbfs(float f) {                // truncate (fast)
    union { float f; unsigned u; } x; x.f = f;
    return (short)(x.u >> 16);
}
static __device__ inline float fexp2(float x) {
    return __builtin_amdgcn_exp2f(x);
}

// async global->LDS, 16B per lane; lds dest must be wave-uniform base
static __device__ inline void async16(const unsigned short* g, unsigned short* l) {
    __builtin_amdgcn_global_load_lds(
        (const __attribute__((address_space(1))) unsigned int*)g,
        (__attribute__((address_space(3))) unsigned int*)l, 16, 0, 0);
}

// ---------------------------------------------------------------------------
// Fused input casts: x -> xA (A-frag), Wqkv -> WB (B-frag), Wproj -> WpB.
// Pads elsewhere (qB/kF/vF/ctxA) stay 0xAA poison — poison bf16 is ~2^-85
// (finite tiny) and every pad read downstream is masked.
__global__ __launch_bounds__(256)
void cast_all(const float* __restrict__ x, const float* __restrict__ Wqkv,
              const float* __restrict__ Wproj,
              unsigned short* __restrict__ xA, unsigned short* __restrict__ WB,
              unsigned short* __restrict__ WpB)
{
    int blk = blockIdx.x;
    int tid = threadIdx.x;
    if (blk < CAST_X_BLK) {
        int s = blk * 256 + tid;                    // < 405504
        int ml = s & 15, q = (s >> 4) & 3;
        int t2 = s >> 6;
        int mt = t2 % MT16, kc = t2 / MT16;
        int m = mt * 16 + ml, k = kc * 32 + q * 8;
        uint4 pk = {0u, 0u, 0u, 0u};
        if (m < M_ROWS) {
            float4 a = *(const float4*)&x[(size_t)m * 768 + k];
            float4 b2 = *(const float4*)&x[(size_t)m * 768 + k + 4];
            pk.x = (unsigned)f2bf(a.x)  | ((unsigned)f2bf(a.y)  << 16);
            pk.y = (unsigned)f2bf(a.z)  | ((unsigned)f2bf(a.w)  << 16);
            pk.z = (unsigned)f2bf(b2.x) | ((unsigned)f2bf(b2.y) << 16);
            pk.w = (unsigned)f2bf(b2.z) | ((unsigned)f2bf(b2.w) << 16);
        }
        *(uint4*)&xA[(size_t)s * 8] = pk;
        return;
    }
    const float* W;
    unsigned short* WO;
    int N, NT, s;
    if (blk < CAST_X_BLK + CAST_WQKV_BLK) {
        W = Wqkv; WO = WB; N = 2304; NT = 144;
        s = (blk - CAST_X_BLK) * 256 + tid;
    } else {
        W = Wproj; WO = WpB; N = 768; NT = 48;
        s = (blk - CAST_X_BLK - CAST_WQKV_BLK) * 256 + tid;
    }
    int nl = s & 15, q = (s >> 4) & 3;
    int t2 = s >> 6;
    int nt = t2 % NT, kc = t2 / NT;
    int n = nt * 16 + nl, k = kc * 32 + q * 8;
    unsigned hv[8];
#pragma unroll
    for (int e = 0; e < 8; ++e)
        hv[e] = f2bf(W[(size_t)(k + e) * N + n]);
    uint4 pk;
    pk.x = hv[0] | (hv[1] << 16);
    pk.y = hv[2] | (hv[3] << 16);
    pk.z = hv[4] | (hv[5] << 16);
    pk.w = hv[6] | (hv[7] << 16);
    *(uint4*)&WO[(size_t)s * 8] = pk;
}

// ---------------------------------------------------------------------------
// MFMA bf16 GEMM, 128x128 tile, 4 waves x (4x4 of 16x16x32), BK=32.
// mode 0 scatters: qB (B-frag x32, xQSCALE), kF (A-frag x32),
//                  vF (B-frag for 16x16x16: k=j quad*4+e, n=d&15)
__global__ __launch_bounds__(256, 2)
void gemm_mfma(const unsigned short* __restrict__ Af,
               const unsigned short* __restrict__ Bf,
               int Nt16, int mode,
               unsigned short* __restrict__ qB, unsigned short* __restrict__ kF,
               unsigned short* __restrict__ vF,
               float* __restrict__ outp, const float* __restrict__ bias)
{
    __shared__ __align__(16) unsigned short ldsA[4096];
    __shared__ __align__(16) unsigned short ldsB[4096];
    const int tid = threadIdx.x;
    const int ln = tid & 63, w = tid >> 6;
    const int wm = w >> 1, wn = w & 1;
    const int mb = blockIdx.x, nb = blockIdx.y;

    floatx4 acc[4][4];
#pragma unroll
    for (int mt = 0; mt < 4; ++mt)
#pragma unroll
        for (int nt = 0; nt < 4; ++nt)
            acc[mt][nt] = (floatx4){0.f, 0.f, 0.f, 0.f};

    for (int kc = 0; kc < KC24; ++kc) {
        const unsigned short* gA = Af + ((size_t)(kc * MT16 + mb * 8)) * 512;
        const unsigned short* gB = Bf + ((size_t)(kc * Nt16 + nb * 8)) * 512;
        async16(gA + (size_t)(w * 128 + ln) * 8,      &ldsA[w * 1024]);
        async16(gA + (size_t)(w * 128 + 64 + ln) * 8, &ldsA[w * 1024 + 512]);
        async16(gB + (size_t)(w * 128 + ln) * 8,      &ldsB[w * 1024]);
        async16(gB + (size_t)(w * 128 + 64 + ln) * 8, &ldsB[w * 1024 + 512]);
        __syncthreads();

        short8 Am[4], Bn[4];
#pragma unroll
        for (int mt = 0; mt < 4; ++mt)
            Am[mt] = *(const short8*)&ldsA[((wm * 4 + mt) * 64 + ln) * 8];
#pragma unroll
        for (int nt = 0; nt < 4; ++nt)
            Bn[nt] = *(const short8*)&ldsB[((wn * 4 + nt) * 64 + ln) * 8];
#pragma unroll
        for (int mt = 0; mt < 4; ++mt)
#pragma unroll
            for (int nt = 0; nt < 4; ++nt)
                acc[mt][nt] = __builtin_amdgcn_mfma_f32_16x16x32_bf16(
                    Am[mt], Bn[nt], acc[mt][nt], 0, 0, 0);
        __syncthreads();
    }

    const int q = ln >> 4, l15 = ln & 15;
    if (mode == 1) {
#pragma unroll
        for (int nt = 0; nt < 4; ++nt) {
            int gn = nb * 128 + wn * 64 + nt * 16 + l15;
            float bv = bias[gn];
#pragma unroll
            for (int mt = 0; mt < 4; ++mt) {
                int gmb = mb * 128 + wm * 64 + mt * 16 + q * 4;
#pragma unroll
                for (int r = 0; r < 4; ++r) {
                    int gm = gmb + r;
                    if (gm < M_ROWS)
                        outp[(size_t)gm * 768 + gn] = acc[mt][nt][r] + bv;
                }
            }
        }
    } else {
#pragma unroll
        for (int nt = 0; nt < 4; ++nt) {
            int gn = nb * 128 + wn * 64 + nt * 16 + l15;
            int s = (gn >= 1536) ? 2 : (gn >= 768 ? 1 : 0);
            int rr = gn - s * Cc;
            int h = rr >> 6, d = rr & 63;
#pragma unroll
            for (int mt = 0; mt < 4; ++mt) {
                int gmb = mb * 128 + wm * 64 + mt * 16 + q * 4;
#pragma unroll
                for (int r = 0; r < 4; ++r) {
                    int gm = gmb + r;
                    if (gm >= M_ROWS) continue;
                    int b = gm / Nn;
                    int n = gm - b * Nn;
                    int bh = b * Hh + h;
                    float val = acc[mt][nt][r];
                    if (s == 0) {
                        int idx = (((bh * IT_TILES + (n >> 4)) * 2 + (d >> 5)) * 512)
                                  + ((((d & 31) >> 3) * 16 + (n & 15)) * 8) + (d & 7);
                        qB[idx] = f2bf(val * QSCALE);
                    } else if (s == 1) {
                        size_t idx = ((((size_t)bh * JT16 + (n >> 4)) * 2 + (d >> 5)) * 64
                                      + ((d >> 3) & 3) * 16 + (n & 15)) * 8 + (d & 7);
                        kF[idx] = f2bf(val);
                    } else {
                        // V as 16x16x16 B-frag: tile=(n>>4), dt=(d>>4),
                        // lane=((n>>2)&3)*16 + (d&15), elem=n&3
                        size_t idx = ((((size_t)bh * JT16 + (n >> 4)) * 4 + (d >> 4)) * 64
                                      + ((n >> 2) & 3) * 16 + (d & 15)) * 4 + (n & 3);
                        vF[idx] = f2bf(val);
                    }
                }
            }
        }
    }
}

// ---------------------------------------------------------------------------
// Pass A: SINGLE-QK colsum, no global atomics.  expS stored as fp8 e4m3 in
// LDS (37.4 KB vs 74.2 KB bf16) -> 4 blocks/CU instead of 2.  e4m3 rel err
// <=6%/elem averages out over 12300 terms (~5e-7 on global_ucb, margin
// ~1.5e-3).  Range [2^-9, 147] within e4m3 [2^-9, 448].
__global__ __launch_bounds__(256, 4)
void attn_colsum_mfma(const unsigned short* __restrict__ qB,
                      const unsigned short* __restrict__ kF,
                      float* __restrict__ colsum_part)
{
    __shared__ unsigned int expS8[32 * STR4];     // 37,376 B  fp8 [i][j/4]
    __shared__ float red16[16][32];               // 2,048 B
    __shared__ float linv[32];

    const int blk = blockIdx.x;                 // 1584 = 8 * 198
    const int x8 = blk & 7, g = blk >> 3;
    const int bh = x8 * 6 + (g % 6);
    const int ib = g / 6;                        // 0..32
    const int tid = threadIdx.x;
    const int ws = tid >> 6;
    const int ln = tid & 63;
    const int i16 = ln & 15, q = ln >> 4;

    const unsigned short* kBase = kF + (size_t)bh * JT16 * 1024;

    short8 Qf[2][2];
#pragma unroll
    for (int it = 0; it < 2; ++it)
#pragma unroll
        for (int kc = 0; kc < 2; ++kc)
            Qf[it][kc] = *(const short8*)&qB[(((size_t)bh * IT_TILES + ib * 2 + it) * 2 + kc) * 512 + ln * 8];

    float lacc[2][2] = {{0.f, 0.f}, {0.f, 0.f}};

    short8 Kc[2][2], Kn[2][2];
#pragma unroll
    for (int jt = 0; jt < 2; ++jt)
#pragma unroll
        for (int kc = 0; kc < 2; ++kc)
            Kc[jt][kc] = *(const short8*)&kBase[(((ws * 2 + jt) * 2 + kc) * 64 + ln) * 8];

    for (int sw = 0; sw < NSW; ++sw) {
        if (sw + 1 < NSW) {
#pragma unroll
            for (int jt = 0; jt < 2; ++jt)
#pragma unroll
                for (int kc = 0; kc < 2; ++kc)
                    Kn[jt][kc] = *(const short8*)&kBase[((((sw + 1) * 8 + ws * 2 + jt) * 2 + kc) * 64 + ln) * 8];
        }

        floatx4 S[2][2];
#pragma unroll
        for (int it = 0; it < 2; ++it)
#pragma unroll
            for (int jt = 0; jt < 2; ++jt) {
                S[it][jt] = (floatx4){0.f, 0.f, 0.f, 0.f};
#pragma unroll
                for (int kc = 0; kc < 2; ++kc)
                    S[it][jt] = __builtin_amdgcn_mfma_f32_16x16x32_bf16(Kc[jt][kc], Qf[it][kc], S[it][jt], 0, 0, 0);
            }

        const int jbase0 = sw * 128 + ws * 32 + q * 4;
#pragma unroll
        for (int it = 0; it < 2; ++it) {
            const int irow = it * 16 + i16;
#pragma unroll
            for (int jt = 0; jt < 2; ++jt) {
                int jbase = jbase0 + jt * 16;
                float p[4];
#pragma unroll
                for (int r = 0; r < 4; ++r) {
                    float vld = (jbase + r < Nn) ? 1.f : 0.f;
                    p[r] = fexp2(S[it][jt][r]) * vld;
                }
                lacc[it][jt] += (p[0] + p[1]) + (p[2] + p[3]);
                unsigned u = (unsigned)__builtin_amdgcn_cvt_pk_fp8_f32(p[0], p[1], 0, false);
                u = (unsigned)__builtin_amdgcn_cvt_pk_fp8_f32(p[2], p[3], (int)u, true);
                expS8[irow * STR4 + (jbase >> 2)] = u;
            }
        }
#pragma unroll
        for (int jt = 0; jt < 2; ++jt)
#pragma unroll
            for (int kc = 0; kc < 2; ++kc)
                Kc[jt][kc] = Kn[jt][kc];
    }

    __syncthreads();
#pragma unroll
    for (int it = 0; it < 2; ++it)
        red16[ws * 4 + q][it * 16 + i16] = lacc[it][0] + lacc[it][1];
    __syncthreads();
    if (tid < 32) {
        float s = 0.f;
#pragma unroll
        for (int t = 0; t < 16; ++t) s += red16[t][tid];
        int gi = ib * 32 + tid;
        linv[tid] = (gi < Nn) ? 1.f / s : 0.f;
    }
    __syncthreads();

    // weighted column reduction (fp8 decode), coalesced float4 partial store
    float* prow = colsum_part + (size_t)(bh * NIB32 + ib) * JP;
    for (int grp = tid; grp < 288; grp += 256) {
        float a0 = 0.f, a1 = 0.f, a2 = 0.f, a3 = 0.f;
#pragma unroll 8
        for (int i = 0; i < 32; ++i) {
            unsigned v = expS8[i * STR4 + grp];
            float li = linv[i];
            a0 += __builtin_amdgcn_cvt_f32_fp8(v, 0) * li;
            a1 += __builtin_amdgcn_cvt_f32_fp8(v, 1) * li;
            a2 += __builtin_amdgcn_cvt_f32_fp8(v, 2) * li;
            a3 += __builtin_amdgcn_cvt_f32_fp8(v, 3) * li;
        }
        float4 o = {a0, a1, a2, a3};
        *(float4*)&prow[grp * 4] = o;
    }
}

// ---------------------------------------------------------------------------
// UCB: self-zeroes keepP/cnt_b rows (ws is poison!), reduces 396 partials,
// scores, exact top-256 per batch.  cnt_b is per-batch (no atomics).
__global__ __launch_bounds__(1024)
void ucb_topk(const float* __restrict__ colsum_part, const float* __restrict__ ucb_score,
              const int* __restrict__ counter_p,
              float* __restrict__ keepP, float* __restrict__ cnt_b)
{
    const int b = blockIdx.x;
    const int tid = threadIdx.x;
    __shared__ float vals[1024];
    __shared__ int   idxs[1024];

    for (int t = tid; t < JP; t += 1024) {
        keepP[b * JP + t] = 0.f;
        cnt_b[b * JP + t] = 0.f;
    }

    const int j = tid + 1;
    const float* pb = colsum_part + (size_t)b * NPART * JP + j;
    float c0 = 0.f, c1 = 0.f, c2 = 0.f, c3 = 0.f;
#pragma unroll 4
    for (int g2 = 0; g2 < NPART; g2 += 4) {
        c0 += pb[(size_t)(g2 + 0) * JP];
        c1 += pb[(size_t)(g2 + 1) * JP];
        c2 += pb[(size_t)(g2 + 2) * JP];
        c3 += pb[(size_t)(g2 + 3) * JP];
    }
    float cs = (c0 + c1) + (c2 + c3);

    float lc = logf((float)(*counter_p) + 1.0f);
    float s = cs * (1.0f / (float)Nn);
#pragma unroll
    for (int h = 0; h < Hh; ++h)
        s += sqrtf(lc / (ucb_score[h * Nn + j] + 1e-6f));
    s *= (1.0f / (float)Hh);
    vals[tid] = s; idxs[tid] = tid;
    __syncthreads();

    for (int k = 2; k <= 1024; k <<= 1) {
        for (int jj = k >> 1; jj > 0; jj >>= 1) {
            int partner = tid ^ jj;
            if (partner > tid) {
                float v1 = vals[tid], v2 = vals[partner];
                int i1 = idxs[tid], i2 = idxs[partner];
                bool gt = (v1 > v2) || (v1 == v2 && i1 < i2);
                bool desc = ((tid & k) == 0);
                if (desc ? !gt : gt) {
                    vals[tid] = v2; vals[partner] = v1;
                    idxs[tid] = i2; idxs[partner] = i1;
                }
            }
            __syncthreads();
        }
    }

    if (tid < KSEL) {
        int tok = idxs[tid] + 1;
        keepP[b * JP + tok] = 1.f;
        cnt_b[b * JP + tok] = 1.0f / (float)Bb;    // unique tokens: plain store
    }
    if (tid == 0) keepP[b * JP + 0] = 1.f;
}

// ---------------------------------------------------------------------------
// Pass B: masked renormalized context.  64-row i-blocks, grid 816 XCD-
// swizzled, register-double-buffered K/V.  P feeds PV directly via
// mfma_f32_16x16x16bf16_1k (A-layout k=quad*4+e == S C-layout rows).
// launch_bounds(256,2): (256,3) spills (R10 post-mortem).
__global__ __launch_bounds__(256, 2)
void attn_ctx_mfma(const unsigned short* __restrict__ qB,
                   const unsigned short* __restrict__ kF,
                   const unsigned short* __restrict__ vF,
                   const float* __restrict__ keepP, const float* __restrict__ cnt_b,
                   unsigned short* __restrict__ ctxA, float* __restrict__ out2)
{
    __shared__ __align__(16) char smem[25856];
    float* keeps = (float*)smem;                             // [1152] 4608 B
    float* red16 = (float*)(smem + 4608);                    // [16][64] 4096 B
    float* dinv  = (float*)(smem + 8704);                    // [64] 256 B
    float* redC  = (float*)(smem + 8960);                    // [64][66] 16896 B

    const int blk = blockIdx.x;                 // 816 = 8 * 102
    const int x8 = blk & 7, g = blk >> 3;
    const int bh = x8 * 6 + (g % 6);
    const int ib = g / 6;
    const int b = bh / Hh, h = bh % Hh;
    const int tid = threadIdx.x;
    const int ws = tid >> 6;
    const int ln = tid & 63;
    const int i16 = ln & 15, q = ln >> 4;

    // fused score_delta write (out2[t] = sum_b cnt_b[b][t%Nn])
    {
        int t = blk * 256 + tid;
        if (t < Hh * Nn) {
            int n = t % Nn;
            out2[t] = cnt_b[0 * JP + n] + cnt_b[1 * JP + n]
                    + cnt_b[2 * JP + n] + cnt_b[3 * JP + n];
        }
    }

    for (int t = tid; t < JP; t += 256) keeps[t] = keepP[b * JP + t];

    const unsigned short* kBase = kF + (size_t)bh * JT16 * 1024;
    const unsigned short* vBase = vF + (size_t)bh * JT16 * 1024;   // same extent

    short8 Qf[4][2];
#pragma unroll
    for (int it = 0; it < 4; ++it)
#pragma unroll
        for (int kc = 0; kc < 2; ++kc)
            Qf[it][kc] = *(const short8*)&qB[(((size_t)bh * IT_TILES + ib * 4 + it) * 2 + kc) * 512 + ln * 8];

    __syncthreads();                     // keeps staged

    float keepi[4];
#pragma unroll
    for (int it = 0; it < 4; ++it)
        keepi[it] = keeps[(ib * 4 + it) * 16 + i16];

    floatx4 ctxacc[4][4];
#pragma unroll
    for (int it = 0; it < 4; ++it)
#pragma unroll
        for (int dt = 0; dt < 4; ++dt)
            ctxacc[it][dt] = (floatx4){0.f, 0.f, 0.f, 0.f};
    float dsacc[4] = {0.f, 0.f, 0.f, 0.f};

    short8 Kc[2][2], Kn[2][2];
    short4s Vc[2][4], Vn[2][4];
#pragma unroll
    for (int jt = 0; jt < 2; ++jt) {
#pragma unroll
        for (int kc = 0; kc < 2; ++kc)
            Kc[jt][kc] = *(const short8*)&kBase[(((ws * 2 + jt) * 2 + kc) * 64 + ln) * 8];
#pragma unroll
        for (int dt = 0; dt < 4; ++dt)
            Vc[jt][dt] = *(const short4s*)&vBase[(((ws * 2 + jt) * 4 + dt) * 64 + ln) * 4];
    }

    for (int sw = 0; sw < NSW; ++sw) {
        if (sw + 1 < NSW) {
#pragma unroll
            for (int jt = 0; jt < 2; ++jt) {
#pragma unroll
                for (int kc = 0; kc < 2; ++kc)
                    Kn[jt][kc] = *(const short8*)&kBase[((((sw + 1) * 8 + ws * 2 + jt) * 2 + kc) * 64 + ln) * 8];
#pragma unroll
                for (int dt = 0; dt < 4; ++dt)
                    Vn[jt][dt] = *(const short4s*)&vBase[((((sw + 1) * 8 + ws * 2 + jt) * 4 + dt) * 64 + ln) * 4];
            }
        }

        float kjv[2][4], vld[2][4];
#pragma unroll
        for (int jt = 0; jt < 2; ++jt)
#pragma unroll
            for (int r = 0; r < 4; ++r) {
                int jj = sw * 128 + ws * 32 + jt * 16 + q * 4 + r;
                vld[jt][r] = (jj < Nn) ? 1.f : 0.f;
                kjv[jt][r] = keeps[jj];
            }

#pragma unroll
        for (int it = 0; it < 4; ++it) {
            floatx4 S[2];
#pragma unroll
            for (int jt = 0; jt < 2; ++jt) {
                S[jt] = (floatx4){0.f, 0.f, 0.f, 0.f};
#pragma unroll
                for (int kc = 0; kc < 2; ++kc)
                    S[jt] = __builtin_amdgcn_mfma_f32_16x16x32_bf16(Kc[jt][kc], Qf[it][kc], S[jt], 0, 0, 0);
            }
            bool rk = keepi[it] > 0.5f;
#pragma unroll
            for (int jt = 0; jt < 2; ++jt) {
                float p[4];
#pragma unroll
                for (int r = 0; r < 4; ++r) {
                    float w = rk ? vld[jt][r] : kjv[jt][r];
                    p[r] = fexp2(S[jt][r]) * w;
                    dsacc[it] += p[r];
                }
                short4s Pa;
                Pa.x = tbfs(p[0]); Pa.y = tbfs(p[1]);
                Pa.z = tbfs(p[2]); Pa.w = tbfs(p[3]);
#pragma unroll
                for (int dt = 0; dt < 4; ++dt)
                    ctxacc[it][dt] = __builtin_amdgcn_mfma_f32_16x16x16bf16_1k(
                        Pa, Vc[jt][dt], ctxacc[it][dt], 0, 0, 0);
            }
        }

#pragma unroll
        for (int jt = 0; jt < 2; ++jt) {
#pragma unroll
            for (int kc = 0; kc < 2; ++kc)
                Kc[jt][kc] = Kn[jt][kc];
#pragma unroll
            for (int dt = 0; dt < 4; ++dt)
                Vc[jt][dt] = Vn[jt][dt];
        }
    }

    // denominator reduce
    __syncthreads();
#pragma unroll
    for (int it = 0; it < 4; ++it) red16[(ws * 4 + q) * 64 + it * 16 + i16] = dsacc[it];
    __syncthreads();
    if (tid < 64) {
        float s = 0.f;
#pragma unroll
        for (int t = 0; t < 16; ++t) s += red16[t * 64 + tid];
        dinv[tid] = 1.f / (s + 1e-8f);
    }
    // cross-wave ctx reduce into redC
    for (int w = 0; w < 4; ++w) {
        __syncthreads();
        if (ws == w) {
#pragma unroll
            for (int it = 0; it < 4; ++it)
#pragma unroll
                for (int dt = 0; dt < 4; ++dt)
#pragma unroll
                    for (int r = 0; r < 4; ++r) {
                        int i = it * 16 + q * 4 + r;
                        int d = dt * 16 + i16;
                        float v = ctxacc[it][dt][r];
                        redC[i * 66 + d] = (w == 0) ? v : (redC[i * 66 + d] + v);
                    }
        }
    }
    __syncthreads();
    // write ctxA in A-fragment order: m = b*Nn+gi, k = h*64+d
#pragma unroll
    for (int rep = 0; rep < 2; ++rep) {
        int s2 = tid + rep * 256;          // < 512 : i(6b) x dc(3b)
        int i = s2 >> 3, dc = s2 & 7;
        int gi = ib * 64 + i;
        if (gi < Nn) {
            int m = b * Nn + gi;
            float dv = dinv[i];
            const float* src = &redC[i * 66 + dc * 8];
            uint4 pk;
            pk.x = (unsigned)f2bf(src[0] * dv) | ((unsigned)f2bf(src[1] * dv) << 16);
            pk.y = (unsigned)f2bf(src[2] * dv) | ((unsigned)f2bf(src[3] * dv) << 16);
            pk.z = (unsigned)f2bf(src[4] * dv) | ((unsigned)f2bf(src[5] * dv) << 16);
            pk.w = (unsigned)f2bf(src[6] * dv) | ((unsigned)f2bf(src[7] * dv) << 16);
            int kc2 = h * 2 + (dc >> 2);
            int q2 = dc & 3;
            size_t idx = (((size_t)(kc2 * MT16 + (m >> 4))) * 64 + q2 * 16 + (m & 15)) * 8;
            *(uint4*)&ctxA[idx] = pk;
        }
    }
}

// ---------------------------------------------------------------------------
extern "C" void kernel_launch(void* const* d_in, const int* in_sizes, int n_in,
                              void* d_out, int out_size, void* d_ws, size_t ws_size,
                              hipStream_t stream) {
    const float* x     = (const float*)d_in[0];
    const float* ucb   = (const float*)d_in[1];
    const float* Wqkv  = (const float*)d_in[2];
    const float* Wproj = (const float*)d_in[3];
    const float* bproj = (const float*)d_in[4];
    const int*   counter = (const int*)d_in[5];

    unsigned short* qB = (unsigned short*)d_ws;      // 3,342,336 sh
    unsigned short* kF = qB + 3342336;               // 3,538,944 sh
    unsigned short* vF = kF + 3538944;               // 3,538,944 sh
    float* keepP    = (float*)(vF + 3538944);        // 4608 f
    float* cnt_b    = keepP + 4608;                  // 4608 f
    unsigned short* ctxA = (unsigned short*)(cnt_b + 4608);  // 3,244,032 sh
    unsigned short* xA   = ctxA + 3244032;           // 3,244,032 sh
    unsigned short* WB   = xA + 3244032;             // 1,769,472 sh
    unsigned short* WpB  = WB + 1769472;             // 589,824 sh
    float* colsum_part = (float*)(WpB + 589824);     // 1,824,768 f

    float* out  = (float*)d_out;                     // [B,N,C]
    float* out2 = out + 3148800;                     // [H,N]

    cast_all<<<dim3(CAST_X_BLK + CAST_WQKV_BLK + CAST_WPROJ_BLK), dim3(256), 0, stream>>>(
        x, Wqkv, Wproj, xA, WB, WpB);
    gemm_mfma<<<dim3(33, 18), dim3(256), 0, stream>>>(
        xA, WB, 144, 0, qB, kF, vF, nullptr, nullptr);
    attn_colsum_mfma<<<dim3(8 * 198), dim3(256), 0, stream>>>(qB, kF, colsum_part);
    ucb_topk<<<dim3(Bb), dim3(1024), 0, stream>>>(colsum_part, ucb, counter, keepP, cnt_b);
    attn_ctx_mfma<<<dim3(8 * 102), dim3(256), 0, stream>>>(qB, kF, vF, keepP, cnt_b, ctxA, out2);
    gemm_mfma<<<dim3(33, 6), dim3(256), 0, stream>>>(
        ctxA, WpB, 48, 1, nullptr, nullptr, nullptr, out, bproj);
}